// Round 3
// baseline (145.104 us; speedup 1.0000x reference)
//
#include <hip/hip_runtime.h>
#include <hip/hip_fp16.h>

#define N_L 8

// ---------------------------------------------------------------------------
// Scatter semantics (reference): full[fixed_indices] = fixed_params;
// full[sorted complement] = trainable_params in order. For vertex v:
// binary-search v in sorted fidx; found at j -> fixed[j], else trainable[v-j].
// ---------------------------------------------------------------------------
__device__ __forceinline__ void softmax8(const float* __restrict__ src, float p[N_L]) {
  float4 a = *(const float4*)src;
  float4 b = *(const float4*)(src + 4);
  p[0] = a.x; p[1] = a.y; p[2] = a.z; p[3] = a.w;
  p[4] = b.x; p[5] = b.y; p[6] = b.z; p[7] = b.w;
  float m = p[0];
#pragma unroll
  for (int i = 1; i < N_L; ++i) m = fmaxf(m, p[i]);
  float s = 0.f;
#pragma unroll
  for (int i = 0; i < N_L; ++i) { p[i] = __expf(p[i] - m); s += p[i]; }
  float r = 1.0f / s;
#pragma unroll
  for (int i = 0; i < N_L; ++i) p[i] *= r;
}

// Block (256 threads = 4 waves) sum reduction; result valid on thread 0.
__device__ __forceinline__ float block_reduce_sum(float v, float* smem) {
#pragma unroll
  for (int off = 32; off > 0; off >>= 1) v += __shfl_down(v, off, 64);
  int lane = threadIdx.x & 63;
  int wid  = threadIdx.x >> 6;
  if (lane == 0) smem[wid] = v;
  __syncthreads();
  if (threadIdx.x < 4) {
    v = smem[threadIdx.x];
    v += __shfl_down(v, 2, 64);
    v += __shfl_down(v, 1, 64);
  }
  return v;
}

// ---------------------------------------------------------------------------
// Materialize softmax table P (nV x 8 fp16 = 16B/row) into workspace.
// fidx staged in LDS -> binary search hits LDS, not global.
// Also zero-inits the accumulator + done-counter for the gather kernel.
// ---------------------------------------------------------------------------
__global__ __launch_bounds__(256) void materialize_P(
    const float* __restrict__ tr, const float* __restrict__ fx,
    const int* __restrict__ fidx, int nF, int nV,
    __half* __restrict__ P, double* __restrict__ acc,
    unsigned int* __restrict__ cnt) {
  __shared__ int sf[1024];
  const bool useLds = (nF <= 1024);
  if (useLds) {
    for (int j = threadIdx.x; j < nF; j += 256) sf[j] = fidx[j];
    __syncthreads();
  }
  int v = blockIdx.x * 256 + threadIdx.x;
  if (v == 0) { acc[0] = 0.0; cnt[0] = 0u; }
  if (v >= nV) return;

  const int* __restrict__ tab = useLds ? sf : fidx;
  int lo = 0, hi = nF;
  while (lo < hi) {
    int mid = (lo + hi) >> 1;
    if (tab[mid] < v) lo = mid + 1; else hi = mid;
  }
  const float* src = (lo < nF && tab[lo] == v) ? (fx + (size_t)lo * N_L)
                                               : (tr + (size_t)(v - lo) * N_L);
  float p[N_L];
  softmax8(src, p);

  __half2 h0 = __floats2half2_rn(p[0], p[1]);
  __half2 h1 = __floats2half2_rn(p[2], p[3]);
  __half2 h2 = __floats2half2_rn(p[4], p[5]);
  __half2 h3 = __floats2half2_rn(p[6], p[7]);
  uint4 raw;
  raw.x = *(const unsigned int*)&h0;
  raw.y = *(const unsigned int*)&h1;
  raw.z = *(const unsigned int*)&h2;
  raw.w = *(const unsigned int*)&h3;
  *(uint4*)(P + (size_t)v * N_L) = raw;
}

__device__ __forceinline__ void load_row_h(const __half* __restrict__ P, int v,
                                           float p[N_L]) {
  uint4 raw = *(const uint4*)(P + (size_t)v * N_L);
  __half2 h0, h1, h2, h3;
  *(unsigned int*)&h0 = raw.x;
  *(unsigned int*)&h1 = raw.y;
  *(unsigned int*)&h2 = raw.z;
  *(unsigned int*)&h3 = raw.w;
  float2 f;
  f = __half22float2(h0); p[0] = f.x; p[1] = f.y;
  f = __half22float2(h1); p[2] = f.x; p[3] = f.y;
  f = __half22float2(h2); p[4] = f.x; p[5] = f.y;
  f = __half22float2(h3); p[6] = f.x; p[7] = f.y;
}

// ---------------------------------------------------------------------------
// Fused pair+triple gather, 2 simplices per thread, finalize fused via
// done-counter (last block writes out).
// Pair term:   -(p.q)                         [+2/pair in cst]
// Triple term: -4*(d01+d02+d12) + (16/3)*T    [+8/tri in cst]
// ---------------------------------------------------------------------------
#define BATCH 2
#define ITEMS_PER_BLOCK (256 * BATCH)

__global__ __launch_bounds__(256) void gather_energy(
    const int* __restrict__ s1, int nP,
    const int* __restrict__ s2, int nT,
    const __half* __restrict__ P, double* __restrict__ acc,
    unsigned int* __restrict__ cnt, int pairBlocks, int totalBlocks,
    float* __restrict__ out, double cst) {
  __shared__ float smem[4];
  float local = 0.f;

  if ((int)blockIdx.x < pairBlocks) {
    int base = blockIdx.x * ITEMS_PER_BLOCK + threadIdx.x;
#pragma unroll
    for (int u = 0; u < BATCH; ++u) {
      int i = base + u * 256;
      if (i < nP) {
        int2 vv = ((const int2*)s1)[i];
        float a[N_L], b[N_L];
        load_row_h(P, vv.x, a);
        load_row_h(P, vv.y, b);
        float d = 0.f;
#pragma unroll
        for (int t = 0; t < N_L; ++t) d += a[t] * b[t];
        local -= d;
      }
    }
  } else {
    int base = (blockIdx.x - pairBlocks) * ITEMS_PER_BLOCK + threadIdx.x;
#pragma unroll
    for (int u = 0; u < BATCH; ++u) {
      int i = base + u * 256;
      if (i < nT) {
        int v0 = s2[3 * i + 0];
        int v1 = s2[3 * i + 1];
        int v2 = s2[3 * i + 2];
        float a[N_L], b[N_L], c[N_L];
        load_row_h(P, v0, a);
        load_row_h(P, v1, b);
        load_row_h(P, v2, c);
        float d01 = 0.f, d02 = 0.f, d12 = 0.f, t3 = 0.f;
#pragma unroll
        for (int t = 0; t < N_L; ++t) {
          d01 += a[t] * b[t];
          d02 += a[t] * c[t];
          d12 += b[t] * c[t];
          t3  += a[t] * b[t] * c[t];
        }
        local += -4.0f * (d01 + d02 + d12) + (16.0f / 3.0f) * t3;
      }
    }
  }

  float bsum = block_reduce_sum(local, smem);
  if (threadIdx.x == 0) {
    atomicAdd(acc, (double)bsum);
    __threadfence();
    unsigned int done = atomicAdd(cnt, 1u);
    if (done == (unsigned int)(totalBlocks - 1)) {
      double total = atomicAdd(acc, 0.0);  // coherent read
      out[0] = (float)(cst + total);
    }
  }
}

// ---------------------------------------------------------------------------
// Fallback path (ws too small): fully fused per-simplex softmax.
// ---------------------------------------------------------------------------
__global__ void init_acc(double* acc) { acc[0] = 0.0; }

__device__ __forceinline__ void load_P_row_fused(int v,
                                                 const float* __restrict__ tr,
                                                 const float* __restrict__ fx,
                                                 const int* __restrict__ fidx,
                                                 int nF, float p[N_L]) {
  int lo = 0, hi = nF;
  while (lo < hi) {
    int mid = (lo + hi) >> 1;
    if (fidx[mid] < v) lo = mid + 1; else hi = mid;
  }
  const float* src = (lo < nF && fidx[lo] == v) ? (fx + (size_t)lo * N_L)
                                                : (tr + (size_t)(v - lo) * N_L);
  softmax8(src, p);
}

__global__ __launch_bounds__(256) void pair_kernel_fused(
    const int* __restrict__ simp, int n,
    const float* __restrict__ tr, const float* __restrict__ fx,
    const int* __restrict__ fidx, int nF, double* __restrict__ acc) {
  __shared__ float smem[4];
  int i = blockIdx.x * blockDim.x + threadIdx.x;
  float local = 0.f;
  if (i < n) {
    int2 vv = ((const int2*)simp)[i];
    float p[N_L], q[N_L];
    load_P_row_fused(vv.x, tr, fx, fidx, nF, p);
    load_P_row_fused(vv.y, tr, fx, fidx, nF, q);
    float d = 0.f;
#pragma unroll
    for (int t = 0; t < N_L; ++t) d += p[t] * q[t];
    local = -d;
  }
  float bsum = block_reduce_sum(local, smem);
  if (threadIdx.x == 0) atomicAdd(acc, (double)bsum);
}

__global__ __launch_bounds__(256) void triple_kernel_fused(
    const int* __restrict__ simp, int n,
    const float* __restrict__ tr, const float* __restrict__ fx,
    const int* __restrict__ fidx, int nF, double* __restrict__ acc) {
  __shared__ float smem[4];
  int i = blockIdx.x * blockDim.x + threadIdx.x;
  float local = 0.f;
  if (i < n) {
    int v0 = simp[3 * i + 0];
    int v1 = simp[3 * i + 1];
    int v2 = simp[3 * i + 2];
    float p[N_L], q[N_L], r[N_L];
    load_P_row_fused(v0, tr, fx, fidx, nF, p);
    load_P_row_fused(v1, tr, fx, fidx, nF, q);
    load_P_row_fused(v2, tr, fx, fidx, nF, r);
    float d01 = 0.f, d02 = 0.f, d12 = 0.f, t3 = 0.f;
#pragma unroll
    for (int t = 0; t < N_L; ++t) {
      d01 += p[t] * q[t];
      d02 += p[t] * r[t];
      d12 += q[t] * r[t];
      t3  += p[t] * q[t] * r[t];
    }
    local = -4.0f * (d01 + d02 + d12) + (16.0f / 3.0f) * t3;
  }
  float bsum = block_reduce_sum(local, smem);
  if (threadIdx.x == 0) atomicAdd(acc, (double)bsum);
}

__global__ void finalize(const double* __restrict__ acc,
                         float* __restrict__ out, double cst) {
  out[0] = (float)(cst + acc[0]);
}

extern "C" void kernel_launch(void* const* d_in, const int* in_sizes, int n_in,
                              void* d_out, int out_size, void* d_ws, size_t ws_size,
                              hipStream_t stream) {
  const float* tr   = (const float*)d_in[0];  // (N_V-N_FIXED, 8) f32
  const float* fx   = (const float*)d_in[1];  // (N_FIXED, 8) f32
  const int*   fidx = (const int*)d_in[2];    // (N_FIXED,) i32 (sorted)
  const int*   s1   = (const int*)d_in[3];    // (nP, 2) i32
  const int*   s2   = (const int*)d_in[4];    // (nT, 3) i32

  int nF = in_sizes[2];
  int nP = in_sizes[3] / 2;
  int nT = in_sizes[4] / 3;
  int nV = (in_sizes[0] + in_sizes[1]) / N_L;

  double*       acc = (double*)d_ws;                        // @0, 8B
  unsigned int* cnt = (unsigned int*)((char*)d_ws + 16);    // @16, 4B
  __half*       P   = (__half*)((char*)d_ws + 256);         // nV*8 fp16
  float*        out = (float*)d_out;

  size_t need = 256 + (size_t)nV * N_L * sizeof(__half);
  double cst = 2.0 * (double)nP + 8.0 * (double)nT;

  if (ws_size >= need) {
    int mBlocks = (nV + 255) / 256;
    materialize_P<<<mBlocks, 256, 0, stream>>>(tr, fx, fidx, nF, nV, P, acc, cnt);
    int pairBlocks = (nP + ITEMS_PER_BLOCK - 1) / ITEMS_PER_BLOCK;
    int triBlocks  = (nT + ITEMS_PER_BLOCK - 1) / ITEMS_PER_BLOCK;
    int totalBlocks = pairBlocks + triBlocks;
    gather_energy<<<totalBlocks, 256, 0, stream>>>(
        s1, nP, s2, nT, P, acc, cnt, pairBlocks, totalBlocks, out, cst);
  } else {
    init_acc<<<1, 1, 0, stream>>>(acc);
    pair_kernel_fused<<<(nP + 255) / 256, 256, 0, stream>>>(s1, nP, tr, fx, fidx, nF, acc);
    triple_kernel_fused<<<(nT + 255) / 256, 256, 0, stream>>>(s2, nT, tr, fx, fidx, nF, acc);
    finalize<<<1, 1, 0, stream>>>(acc, out, cst);
  }
}